// Round 1
// baseline (1726.595 us; speedup 1.0000x reference)
//
#include <hip/hip_runtime.h>
#include <hip/hip_bf16.h>
#include <stdint.h>

#define N_NODES 300000
#define N_EDGES 4000000
#define IC 128
#define OC 64
#define NREL 7
#define NTYP 4
#define NRELT 11   // 7 relations + 4 root pseudo-relations
#define LDS_STRIDE 136  // ushorts per A row (128 + 8 pad -> 272B, 16B aligned, bank-balanced)

typedef __attribute__((ext_vector_type(8))) short short8;
typedef __attribute__((ext_vector_type(4))) float f32x4;

__device__ __forceinline__ uint32_t f32_to_bf16_rne(float f) {
    uint32_t b = __float_as_uint(f);
    return (b + 0x7fffu + ((b >> 16) & 1u)) >> 16;
}
__device__ __forceinline__ uint32_t pack_bf16(float lo, float hi) {
    return f32_to_bf16_rne(lo) | (f32_to_bf16_rne(hi) << 16);
}

// ---- K0: x fp32 -> bf16 (8 floats / thread) ----
__global__ void k_cvt_x(const float* __restrict__ x, uint32_t* __restrict__ xb) {
    int i = blockIdx.x * blockDim.x + threadIdx.x;
    const float4* xf = (const float4*)x;
    float4 a = xf[2 * i], b = xf[2 * i + 1];
    uint4 o;
    o.x = pack_bf16(a.x, a.y); o.y = pack_bf16(a.z, a.w);
    o.z = pack_bf16(b.x, b.y); o.w = pack_bf16(b.z, b.w);
    ((uint4*)xb)[i] = o;
}

// ---- K0b: W_rel [7][128][64] ++ W_root [4][128][64] -> Wt bf16 [11][64][128] (o-major, k-contig) ----
__global__ void k_cvt_w(const float* __restrict__ Wrel, const float* __restrict__ Wroot,
                        uint16_t* __restrict__ Wt) {
    int i = blockIdx.x * blockDim.x + threadIdx.x;   // i = rel*8192 + o*128 + k
    int rel = i >> 13, rem = i & 8191, o = rem >> 7, k = rem & 127;
    float v = (rel < NREL) ? Wrel[(rel * IC + k) * OC + o]
                           : Wroot[((rel - NREL) * IC + k) * OC + o];
    Wt[i] = (uint16_t)f32_to_bf16_rne(v);
}

// ---- K1: dst-degree histogram ----
__global__ void k_hist(const int* __restrict__ ei, int* __restrict__ deg) {
    int e = blockIdx.x * blockDim.x + threadIdx.x;
    atomicAdd(&deg[ei[N_EDGES + e]], 1);
}

// ---- K2a/b/c: exclusive scan of deg -> offs (and cursor copy) ----
__global__ void k_scan1(const int* __restrict__ deg, int* __restrict__ offs,
                        int* __restrict__ bsum) {
    __shared__ int s[1024];
    int t = threadIdx.x, i = blockIdx.x * 1024 + t;
    int v = (i < N_NODES) ? deg[i] : 0;
    s[t] = v; __syncthreads();
    for (int d = 1; d < 1024; d <<= 1) {
        int add = (t >= d) ? s[t - d] : 0;
        __syncthreads();
        s[t] += add;
        __syncthreads();
    }
    if (i < N_NODES) offs[i] = s[t] - v;
    if (t == 1023) bsum[blockIdx.x] = s[t];
}

__global__ void k_scan2(int* __restrict__ bsum, int nblk) {
    __shared__ int s[512];
    int t = threadIdx.x;
    int v = (t < nblk) ? bsum[t] : 0;
    s[t] = v; __syncthreads();
    for (int d = 1; d < 512; d <<= 1) {
        int add = (t >= d) ? s[t - d] : 0;
        __syncthreads();
        s[t] += add;
        __syncthreads();
    }
    if (t < nblk) bsum[t] = s[t] - v;
}

__global__ void k_scan3(int* __restrict__ offs, const int* __restrict__ bsum,
                        int* __restrict__ cur) {
    int i = blockIdx.x * 256 + threadIdx.x;
    if (i < N_NODES) {
        int v = offs[i] + bsum[i >> 10];
        offs[i] = v;
        cur[i] = v;
    }
}

// ---- K3: scatter edges into dst-sorted order, packed (src<<3)|et ----
__global__ void k_scatter(const int* __restrict__ ei, const int* __restrict__ et,
                          int* __restrict__ cur, int* __restrict__ sorted) {
    int e = blockIdx.x * 256 + threadIdx.x;
    int d = ei[N_EDGES + e];
    int pos = atomicAdd(&cur[d], 1);
    sorted[pos] = (ei[e] << 3) | et[e];
}

// ---- K4: fused aggregate + MFMA GEMM. 1 block = 16 dst nodes. ----
__global__ __launch_bounds__(256, 2)
void k_main(const uint32_t* __restrict__ xb_u, const uint16_t* __restrict__ Wt,
            const int* __restrict__ offs, const int* __restrict__ deg,
            const int* __restrict__ sorted, const int* __restrict__ node_type,
            const float* __restrict__ b_root, float* __restrict__ out) {
    __shared__ uint16_t A[NRELT * 16 * LDS_STRIDE];
    int t = threadIdx.x, lane = t & 63, wave = t >> 6;
    int dst_base = blockIdx.x * 16;
    uint32_t* A32 = (uint32_t*)A;   // row stride = 68 uints

    // Phase 1+2: each wave accumulates 4 dst slots, writes scaled bf16 A-rows
    for (int sl = 0; sl < 4; ++sl) {
        int slot = wave * 4 + sl;
        int dst = dst_base + slot;
        int base = offs[dst], dcnt = deg[dst];
        float a0[NREL], a1[NREL]; int cn[NREL];
        #pragma unroll
        for (int r = 0; r < NREL; ++r) { a0[r] = 0.f; a1[r] = 0.f; cn[r] = 0; }

        for (int c0 = 0; c0 < dcnt; c0 += 64) {
            int nb = min(dcnt - c0, 64);
            int pk = (lane < nb) ? sorted[base + c0 + lane] : 0;
            for (int e = 0; e < nb; ++e) {
                int pe = __shfl(pk, e);          // wave-uniform edge record
                int srcn = pe >> 3, etp = pe & 7;
                uint32_t v = xb_u[srcn * 64 + lane];   // 256B coalesced gather
                float f0 = __uint_as_float(v << 16);
                float f1 = __uint_as_float(v & 0xffff0000u);
                switch (etp) {   // wave-uniform branch
                    case 0: a0[0] += f0; a1[0] += f1; cn[0]++; break;
                    case 1: a0[1] += f0; a1[1] += f1; cn[1]++; break;
                    case 2: a0[2] += f0; a1[2] += f1; cn[2]++; break;
                    case 3: a0[3] += f0; a1[3] += f1; cn[3]++; break;
                    case 4: a0[4] += f0; a1[4] += f1; cn[4]++; break;
                    case 5: a0[5] += f0; a1[5] += f1; cn[5]++; break;
                    default: a0[6] += f0; a1[6] += f1; cn[6]++; break;
                }
            }
        }
        // scaled relation rows (scatter-mean applied here)
        #pragma unroll
        for (int r = 0; r < NREL; ++r) {
            float s = 1.0f / (float)max(cn[r], 1);
            A32[(r * 16 + slot) * 68 + lane] = pack_bf16(a0[r] * s, a1[r] * s);
        }
        // root pseudo-relations: x[dst] masked by node type
        uint32_t xv = xb_u[dst * 64 + lane];
        int nt = node_type[dst];
        #pragma unroll
        for (int tt = 0; tt < NTYP; ++tt)
            A32[((NREL + tt) * 16 + slot) * 68 + lane] = (tt == nt) ? xv : 0u;
    }
    __syncthreads();

    // Phase 3: each wave computes a 16(dst) x 16(out-col) tile, accumulating all 11 rels
    int row = lane & 15, quad = lane >> 4;
    f32x4 c = {0.f, 0.f, 0.f, 0.f};
    for (int rel = 0; rel < NRELT; ++rel) {
        #pragma unroll
        for (int kb = 0; kb < 4; ++kb) {
            // A frag: A[m=row][k = kb*32 + quad*8 + j]
            short8 af = *(const short8*)&A[(rel * 16 + row) * LDS_STRIDE + kb * 32 + quad * 8];
            // B frag: B[k][n=row] = Wt[rel][wave*16+row][k] (k-contiguous)
            short8 bf = *(const short8*)&Wt[(rel * 64 + wave * 16 + row) * 128 + kb * 32 + quad * 8];
            c = __builtin_amdgcn_mfma_f32_16x16x32_bf16(af, bf, c, 0, 0, 0);
        }
    }

    // Epilogue: C layout col=lane&15, row=quad*4+reg; add b_root
    int o = wave * 16 + row;
    #pragma unroll
    for (int rg = 0; rg < 4; ++rg) {
        int slot = quad * 4 + rg;
        int dst = dst_base + slot;
        int nt = node_type[dst];
        out[dst * 64 + o] = c[rg] + b_root[nt * 64 + o];
    }
}

extern "C" void kernel_launch(void* const* d_in, const int* in_sizes, int n_in,
                              void* d_out, int out_size, void* d_ws, size_t ws_size,
                              hipStream_t stream) {
    const float* x      = (const float*)d_in[0];
    const int*   ei     = (const int*)d_in[1];
    const int*   etype  = (const int*)d_in[2];
    const int*   ntype  = (const int*)d_in[3];
    const float* Wrel   = (const float*)d_in[4];
    const float* Wroot  = (const float*)d_in[5];
    const float* broot  = (const float*)d_in[6];
    float* out = (float*)d_out;

    // workspace layout (256B aligned)
    char* ws = (char*)d_ws;
    size_t p = 0;
    auto take = [&](size_t bytes) { size_t r = p; p += (bytes + 255) & ~(size_t)255; return r; };
    uint32_t* xb     = (uint32_t*)(ws + take((size_t)N_NODES * IC * 2)); // 76.8 MB
    uint16_t* Wt     = (uint16_t*)(ws + take((size_t)NRELT * OC * IC * 2));
    int*      deg    = (int*)(ws + take((size_t)N_NODES * 4));
    int*      offs   = (int*)(ws + take((size_t)N_NODES * 4));
    int*      cur    = (int*)(ws + take((size_t)N_NODES * 4));
    int*      bsum   = (int*)(ws + take(4096));
    int*      sorted = (int*)(ws + take((size_t)N_EDGES * 4));
    (void)ws_size; (void)n_in; (void)in_sizes; (void)out_size;

    const int SCAN_BLKS = (N_NODES + 1023) / 1024;   // 293

    k_cvt_x<<<(N_NODES * IC / 8) / 256, 256, 0, stream>>>(x, xb);
    k_cvt_w<<<(NRELT * OC * IC) / 256, 256, 0, stream>>>(Wrel, Wroot, Wt);
    hipMemsetAsync(deg, 0, (size_t)N_NODES * 4, stream);
    k_hist<<<N_EDGES / 256, 256, 0, stream>>>(ei, deg);
    k_scan1<<<SCAN_BLKS, 1024, 0, stream>>>(deg, offs, bsum);
    k_scan2<<<1, 512, 0, stream>>>(bsum, SCAN_BLKS);
    k_scan3<<<(N_NODES + 255) / 256, 256, 0, stream>>>(offs, bsum, cur);
    k_scatter<<<N_EDGES / 256, 256, 0, stream>>>(ei, etype, cur, sorted);
    k_main<<<N_NODES / 16, 256, 0, stream>>>(xb, Wt, offs, deg, sorted, ntype, broot, out);
}